// Round 3
// baseline (1676.338 us; speedup 1.0000x reference)
//
#include <hip/hip_runtime.h>
#include <hip/hip_bf16.h>

#define T_TOK 4096
#define DM    1024
#define FF    2048
#define NE    16
#define NP    8192   // 2*T_TOK pairs
#define LS    56     // LDS row stride in bf16 elems (112B: 16B-aligned, spreads banks)

typedef __bf16 bf16x8 __attribute__((ext_vector_type(8)));
typedef float  f32x4  __attribute__((ext_vector_type(4)));

static __device__ __forceinline__ unsigned short f2bf(float f) {
    union { float f; unsigned u; } v; v.f = f;
    unsigned r = v.u + 0x7fffu + ((v.u >> 16) & 1u);
    return (unsigned short)(r >> 16);
}

static __device__ __forceinline__ ushort4 f4tobf(float4 v) {
    ushort4 c; c.x = f2bf(v.x); c.y = f2bf(v.y); c.z = f2bf(v.z); c.w = f2bf(v.w);
    return c;
}

// ---------------- Router: logits (fp32), top-2, renorm weights; x -> bf16 ----
__global__ __launch_bounds__(256) void k_router(
    const float* __restrict__ x, const float* __restrict__ rw,
    const float* __restrict__ rb, unsigned short* __restrict__ xb,
    int* __restrict__ e0a, int* __restrict__ e1a,
    float* __restrict__ w0a, float* __restrict__ w1a, int* __restrict__ counts)
{
    const int t = blockIdx.x, tid = threadIdx.x;
    float4 xv = ((const float4*)(x + (size_t)t * DM))[tid];
    ((ushort4*)(xb + (size_t)t * DM))[tid] = f4tobf(xv);
    float part[NE];
#pragma unroll
    for (int e = 0; e < NE; ++e) {
        float4 wv = ((const float4*)(rw + (size_t)e * DM))[tid];
        part[e] = xv.x*wv.x + xv.y*wv.y + xv.z*wv.z + xv.w*wv.w;
    }
#pragma unroll
    for (int e = 0; e < NE; ++e) {
        float v = part[e];
#pragma unroll
        for (int off = 32; off > 0; off >>= 1) v += __shfl_down(v, off);
        part[e] = v;
    }
    __shared__ float red[4][NE];
    const int lane = tid & 63, wv_ = tid >> 6;
    if (lane == 0) {
#pragma unroll
        for (int e = 0; e < NE; ++e) red[wv_][e] = part[e];
    }
    __syncthreads();
    if (tid == 0) {
        float lg[NE];
#pragma unroll
        for (int e = 0; e < NE; ++e)
            lg[e] = red[0][e] + red[1][e] + red[2][e] + red[3][e] + rb[e];
        int b0 = 0;
        for (int e = 1; e < NE; ++e) if (lg[e] > lg[b0]) b0 = e;
        int b1 = (b0 == 0) ? 1 : 0;
        for (int e = 0; e < NE; ++e) { if (e == b0) continue; if (lg[e] > lg[b1]) b1 = e; }
        float m  = fmaxf(lg[b0], lg[b1]);
        float x0 = __expf(lg[b0] - m), x1 = __expf(lg[b1] - m);
        float inv = 1.f / (x0 + x1);
        e0a[t] = b0; e1a[t] = b1; w0a[t] = x0 * inv; w1a[t] = x1 * inv;
        atomicAdd(&counts[b0], 1); atomicAdd(&counts[b1], 1);
    }
}

// ---------------- Exclusive scan of 16 counts --------------------------------
__global__ void k_scan(const int* __restrict__ counts, int* __restrict__ offs)
{
    if (threadIdx.x == 0) {
        int s = 0;
        for (int e = 0; e < NE; ++e) { offs[e] = s; s += counts[e]; }
        offs[NE] = s;
    }
}

// ---------------- Scatter token->pair slots ----------------------------------
__global__ __launch_bounds__(256) void k_scatter(
    const int* __restrict__ e0a, const int* __restrict__ e1a,
    const int* __restrict__ offs, int* __restrict__ cursors,
    int* __restrict__ p0a, int* __restrict__ p1a, int* __restrict__ pair_tok)
{
    const int t = blockIdx.x * 256 + threadIdx.x;
    if (t >= T_TOK) return;
    int e0 = e0a[t];
    int p = offs[e0] + atomicAdd(&cursors[e0], 1);
    pair_tok[p] = t; p0a[t] = p;
    int e1 = e1a[t];
    p = offs[e1] + atomicAdd(&cursors[e1], 1);
    pair_tok[p] = t; p1a[t] = p;
}

// ---------------- Grouped GEMM 1: h = silu(X@W1^T) * (X@W3^T) ---------------
// 128(M pairs) x 128(F) tile, BK=32, 512 thr = 8 waves, wave tile 64x32
__global__ __launch_bounds__(512) void k_ffn1(
    const unsigned short* __restrict__ xb, const float* __restrict__ w1g,
    const float* __restrict__ w3g, const int* __restrict__ pair_tok,
    const int* __restrict__ offs, const int* __restrict__ counts,
    unsigned short* __restrict__ h)
{
    const int e = blockIdx.z;
    const int cnt = counts[e];
    const int m0 = blockIdx.x * 128;
    if (m0 >= cnt) return;
    const int base = offs[e];
    const int n0 = blockIdx.y * 128;
    const float* __restrict__ W1 = w1g + (size_t)e * FF * DM;
    const float* __restrict__ W3 = w3g + (size_t)e * FF * DM;

    __shared__ __attribute__((aligned(16))) unsigned short As[128][LS];
    __shared__ __attribute__((aligned(16))) unsigned short B1s[128][LS];
    __shared__ __attribute__((aligned(16))) unsigned short B3s[128][LS];

    const int tid = threadIdx.x;
    const int ar = tid >> 2, aseg = tid & 3;
    const int tok = pair_tok[base + min(m0 + ar, cnt - 1)];
    const unsigned short* __restrict__ xrow = xb + (size_t)tok * DM + aseg * 8;

    const int br = tid >> 3, bseg = tid & 7;
    const float* __restrict__ W1r0 = W1 + (size_t)(n0 + br) * DM + bseg * 4;
    const float* __restrict__ W1r1 = W1 + (size_t)(n0 + br + 64) * DM + bseg * 4;
    const float* __restrict__ W3r0 = W3 + (size_t)(n0 + br) * DM + bseg * 4;
    const float* __restrict__ W3r1 = W3 + (size_t)(n0 + br + 64) * DM + bseg * 4;

    const int wave = tid >> 6, lane = tid & 63;
    const int wm = (wave >> 2) * 64, wn = (wave & 3) * 32;
    const int lr = lane & 15, lk = (lane >> 4) * 8;

    f32x4 acc1[4][2], acc3[4][2];
#pragma unroll
    for (int i = 0; i < 4; ++i)
#pragma unroll
        for (int j = 0; j < 2; ++j) {
            acc1[i][j] = f32x4{0.f, 0.f, 0.f, 0.f};
            acc3[i][j] = f32x4{0.f, 0.f, 0.f, 0.f};
        }

    for (int k0 = 0; k0 < DM; k0 += 32) {
        *(uint4*)&As[ar][aseg * 8] = *(const uint4*)(xrow + k0);
        float4 a0 = *(const float4*)(W1r0 + k0);
        float4 a1 = *(const float4*)(W1r1 + k0);
        float4 c0 = *(const float4*)(W3r0 + k0);
        float4 c1 = *(const float4*)(W3r1 + k0);
        *(ushort4*)&B1s[br][bseg * 4]      = f4tobf(a0);
        *(ushort4*)&B1s[br + 64][bseg * 4] = f4tobf(a1);
        *(ushort4*)&B3s[br][bseg * 4]      = f4tobf(c0);
        *(ushort4*)&B3s[br + 64][bseg * 4] = f4tobf(c1);
        __syncthreads();
        bf16x8 af[4], b1f[2], b3f[2];
#pragma unroll
        for (int i = 0; i < 4; ++i) af[i] = *(const bf16x8*)&As[wm + i*16 + lr][lk];
#pragma unroll
        for (int j = 0; j < 2; ++j) {
            b1f[j] = *(const bf16x8*)&B1s[wn + j*16 + lr][lk];
            b3f[j] = *(const bf16x8*)&B3s[wn + j*16 + lr][lk];
        }
#pragma unroll
        for (int i = 0; i < 4; ++i)
#pragma unroll
            for (int j = 0; j < 2; ++j) {
                acc1[i][j] = __builtin_amdgcn_mfma_f32_16x16x32_bf16(af[i], b1f[j], acc1[i][j], 0, 0, 0);
                acc3[i][j] = __builtin_amdgcn_mfma_f32_16x16x32_bf16(af[i], b3f[j], acc3[i][j], 0, 0, 0);
            }
        __syncthreads();
    }
    const int orb = (lane >> 4) * 4, oc = lane & 15;
#pragma unroll
    for (int i = 0; i < 4; ++i) {
#pragma unroll
        for (int r = 0; r < 4; ++r) {
            int m = m0 + wm + i*16 + orb + r;
            if (m < cnt) {
                size_t prow = (size_t)(base + m) * FF + n0 + wn;
#pragma unroll
                for (int j = 0; j < 2; ++j) {
                    float a = acc1[i][j][r], c = acc3[i][j][r];
                    float hv = (a / (1.f + __expf(-a))) * c;   // silu(a)*c
                    h[prow + j*16 + oc] = f2bf(hv);
                }
            }
        }
    }
}

// ---------------- Grouped GEMM 2: y = h @ W2^T (fp32 out) -------------------
__global__ __launch_bounds__(512) void k_ffn2(
    const unsigned short* __restrict__ h, const float* __restrict__ w2g,
    const int* __restrict__ offs, const int* __restrict__ counts,
    float* __restrict__ y)
{
    const int e = blockIdx.z;
    const int cnt = counts[e];
    const int m0 = blockIdx.x * 128;
    if (m0 >= cnt) return;
    const int base = offs[e];
    const int n0 = blockIdx.y * 128;
    const float* __restrict__ W2 = w2g + (size_t)e * DM * FF;

    __shared__ __attribute__((aligned(16))) unsigned short As[128][LS];
    __shared__ __attribute__((aligned(16))) unsigned short Bs[128][LS];

    const int tid = threadIdx.x;
    const int ar = tid >> 2, aseg = tid & 3;
    const size_t arow = (size_t)min(base + m0 + ar, NP - 1) * FF + aseg * 8;

    const int br = tid >> 3, bseg = tid & 7;
    const float* __restrict__ W2r0 = W2 + (size_t)(n0 + br) * FF + bseg * 4;
    const float* __restrict__ W2r1 = W2 + (size_t)(n0 + br + 64) * FF + bseg * 4;

    const int wave = tid >> 6, lane = tid & 63;
    const int wm = (wave >> 2) * 64, wn = (wave & 3) * 32;
    const int lr = lane & 15, lk = (lane >> 4) * 8;

    f32x4 acc[4][2];
#pragma unroll
    for (int i = 0; i < 4; ++i)
#pragma unroll
        for (int j = 0; j < 2; ++j) acc[i][j] = f32x4{0.f, 0.f, 0.f, 0.f};

    for (int k0 = 0; k0 < FF; k0 += 32) {
        *(uint4*)&As[ar][aseg * 8] = *(const uint4*)(h + arow + k0);
        float4 v0 = *(const float4*)(W2r0 + k0);
        float4 v1 = *(const float4*)(W2r1 + k0);
        *(ushort4*)&Bs[br][bseg * 4]      = f4tobf(v0);
        *(ushort4*)&Bs[br + 64][bseg * 4] = f4tobf(v1);
        __syncthreads();
        bf16x8 af[4], bf[2];
#pragma unroll
        for (int i = 0; i < 4; ++i) af[i] = *(const bf16x8*)&As[wm + i*16 + lr][lk];
#pragma unroll
        for (int j = 0; j < 2; ++j) bf[j] = *(const bf16x8*)&Bs[wn + j*16 + lr][lk];
#pragma unroll
        for (int i = 0; i < 4; ++i)
#pragma unroll
            for (int j = 0; j < 2; ++j)
                acc[i][j] = __builtin_amdgcn_mfma_f32_16x16x32_bf16(af[i], bf[j], acc[i][j], 0, 0, 0);
        __syncthreads();
    }
    const int orb = (lane >> 4) * 4, oc = lane & 15;
#pragma unroll
    for (int i = 0; i < 4; ++i) {
#pragma unroll
        for (int r = 0; r < 4; ++r) {
            int m = m0 + wm + i*16 + orb + r;
            if (m < cnt) {
                size_t yrow = (size_t)(base + m) * DM + n0 + wn;
#pragma unroll
                for (int j = 0; j < 2; ++j) y[yrow + j*16 + oc] = acc[i][j][r];
            }
        }
    }
}

// ---------------- LayerNorm both pair rows + weighted combine ---------------
__global__ __launch_bounds__(256) void k_ln(
    const float* __restrict__ y, const int* __restrict__ p0a, const int* __restrict__ p1a,
    const int* __restrict__ e0a, const int* __restrict__ e1a,
    const float* __restrict__ w0a, const float* __restrict__ w1a,
    const float* __restrict__ lng, const float* __restrict__ lnb,
    float* __restrict__ out)
{
    const int t = blockIdx.x, tid = threadIdx.x;
    const int p0 = p0a[t], p1 = p1a[t], e0 = e0a[t], e1 = e1a[t];
    const float cw0 = w0a[t], cw1 = w1a[t];
    float4 y0 = ((const float4*)(y + (size_t)p0 * DM))[tid];
    float4 y1 = ((const float4*)(y + (size_t)p1 * DM))[tid];
    float s0 = y0.x + y0.y + y0.z + y0.w;
    float q0 = y0.x*y0.x + y0.y*y0.y + y0.z*y0.z + y0.w*y0.w;
    float s1 = y1.x + y1.y + y1.z + y1.w;
    float q1 = y1.x*y1.x + y1.y*y1.y + y1.z*y1.z + y1.w*y1.w;
#pragma unroll
    for (int off = 32; off > 0; off >>= 1) {
        s0 += __shfl_down(s0, off); q0 += __shfl_down(q0, off);
        s1 += __shfl_down(s1, off); q1 += __shfl_down(q1, off);
    }
    __shared__ float rbuf[4][4];
    const int lane = tid & 63, wv_ = tid >> 6;
    if (lane == 0) { rbuf[wv_][0] = s0; rbuf[wv_][1] = q0; rbuf[wv_][2] = s1; rbuf[wv_][3] = q1; }
    __syncthreads();
    float S0 = rbuf[0][0] + rbuf[1][0] + rbuf[2][0] + rbuf[3][0];
    float Q0 = rbuf[0][1] + rbuf[1][1] + rbuf[2][1] + rbuf[3][1];
    float S1 = rbuf[0][2] + rbuf[1][2] + rbuf[2][2] + rbuf[3][2];
    float Q1 = rbuf[0][3] + rbuf[1][3] + rbuf[2][3] + rbuf[3][3];
    const float invD = 1.f / (float)DM;
    float mu0 = S0 * invD, mu1 = S1 * invD;
    float rs0 = rsqrtf(fmaxf(Q0 * invD - mu0 * mu0, 0.f) + 1e-5f);
    float rs1 = rsqrtf(fmaxf(Q1 * invD - mu1 * mu1, 0.f) + 1e-5f);
    float4 g0 = ((const float4*)(lng + (size_t)e0 * DM))[tid];
    float4 b0 = ((const float4*)(lnb + (size_t)e0 * DM))[tid];
    float4 g1 = ((const float4*)(lng + (size_t)e1 * DM))[tid];
    float4 b1 = ((const float4*)(lnb + (size_t)e1 * DM))[tid];
    float4 o;
    o.x = cw0 * ((y0.x - mu0) * rs0 * g0.x + b0.x) + cw1 * ((y1.x - mu1) * rs1 * g1.x + b1.x);
    o.y = cw0 * ((y0.y - mu0) * rs0 * g0.y + b0.y) + cw1 * ((y1.y - mu1) * rs1 * g1.y + b1.y);
    o.z = cw0 * ((y0.z - mu0) * rs0 * g0.z + b0.z) + cw1 * ((y1.z - mu1) * rs1 * g1.z + b1.z);
    o.w = cw0 * ((y0.w - mu0) * rs0 * g0.w + b0.w) + cw1 * ((y1.w - mu1) * rs1 * g1.w + b1.w);
    ((float4*)(out + (size_t)t * DM))[tid] = o;
}

// ---------------- launch -----------------------------------------------------
extern "C" void kernel_launch(void* const* d_in, const int* in_sizes, int n_in,
                              void* d_out, int out_size, void* d_ws, size_t ws_size,
                              hipStream_t stream)
{
    const float* x   = (const float*)d_in[0];
    const float* rw  = (const float*)d_in[1];
    const float* rb  = (const float*)d_in[2];
    const float* w1  = (const float*)d_in[3];
    const float* w2  = (const float*)d_in[4];
    const float* w3  = (const float*)d_in[5];
    const float* lng = (const float*)d_in[6];
    const float* lnb = (const float*)d_in[7];
    float* out = (float*)d_out;
    char* ws = (char*)d_ws;

    const size_t OFF_XB   = 0;                                  // T*D bf16  = 8 MB
    const size_t OFF_H    = OFF_XB + (size_t)T_TOK * DM * 2;    // P*F bf16  = 32 MB
    const size_t OFF_Y    = OFF_H + (size_t)NP * FF * 2;        // P*D f32   = 32 MB
    const size_t OFF_META = OFF_Y + (size_t)NP * DM * 4;

    unsigned short* xb = (unsigned short*)(ws + OFF_XB);
    unsigned short* h  = (unsigned short*)(ws + OFF_H);
    float* y           = (float*)(ws + OFF_Y);
    int* counts   = (int*)(ws + OFF_META);       // 16
    int* cursors  = counts + 16;                 // 16
    int* offs     = counts + 32;                 // 17
    int* e0a      = (int*)(ws + OFF_META + 256);
    int* e1a      = e0a + T_TOK;
    float* w0a    = (float*)(e1a + T_TOK);
    float* w1a    = w0a + T_TOK;
    int* p0a      = (int*)(w1a + T_TOK);
    int* p1a      = p0a + T_TOK;
    int* pair_tok = p1a + T_TOK;

    hipMemsetAsync(ws + OFF_META, 0, 128, stream);  // counts + cursors
    k_router<<<T_TOK, 256, 0, stream>>>(x, rw, rb, xb, e0a, e1a, w0a, w1a, counts);
    k_scan<<<1, 64, 0, stream>>>(counts, offs);
    k_scatter<<<T_TOK / 256, 256, 0, stream>>>(e0a, e1a, offs, cursors, p0a, p1a, pair_tok);
    k_ffn1<<<dim3(32, FF / 128, NE), 512, 0, stream>>>(xb, w1, w3, pair_tok, offs, counts, h);
    k_ffn2<<<dim3(32, DM / 128, NE), 512, 0, stream>>>(h, w2, offs, counts, y);
    k_ln<<<T_TOK, 256, 0, stream>>>(y, p0a, p1a, e0a, e1a, w0a, w1a, lng, lnb, out);
}

// Round 5
// 1513.556 us; speedup vs baseline: 1.1075x; 1.1075x over previous
//
#include <hip/hip_runtime.h>
#include <hip/hip_bf16.h>

#define T_TOK 4096
#define DM    1024
#define FF    2048
#define NE    16
#define NP    8192   // 2*T_TOK pairs
#define LS    56     // fallback-path LDS row stride (bf16 elems)

typedef __bf16 bf16x8 __attribute__((ext_vector_type(8)));
typedef float  f32x4  __attribute__((ext_vector_type(4)));

static __device__ __forceinline__ unsigned short f2bf(float f) {
    union { float f; unsigned u; } v; v.f = f;
    unsigned r = v.u + 0x7fffu + ((v.u >> 16) & 1u);
    return (unsigned short)(r >> 16);
}

static __device__ __forceinline__ ushort4 f4tobf(float4 v) {
    ushort4 c; c.x = f2bf(v.x); c.y = f2bf(v.y); c.z = f2bf(v.z); c.w = f2bf(v.w);
    return c;
}

// async global->LDS, 16B per lane; LDS dest must be wave-uniform base + lane*16
#define GLOAD16(gp, lp) \
    __builtin_amdgcn_global_load_lds((const __attribute__((address_space(1))) unsigned*)(gp), \
                                     (__attribute__((address_space(3))) unsigned*)(lp), 16, 0, 0)

// ---------------- Weight conversion fp32 -> bf16 (streaming) ----------------
__global__ __launch_bounds__(256) void k_convert(
    const float* __restrict__ s, unsigned short* __restrict__ d, int n8)
{
    for (int i = blockIdx.x * 256 + threadIdx.x; i < n8; i += gridDim.x * 256) {
        const float4* sp = (const float4*)s + (size_t)i * 2;
        float4 a = sp[0], b = sp[1];
        union { ushort4 u4[2]; uint4 v; } w;
        w.u4[0] = f4tobf(a); w.u4[1] = f4tobf(b);
        ((uint4*)d)[i] = w.v;
    }
}

// ---------------- Router: logits (fp32), top-2, renorm weights; x -> bf16 ----
__global__ __launch_bounds__(256) void k_router(
    const float* __restrict__ x, const float* __restrict__ rw,
    const float* __restrict__ rb, unsigned short* __restrict__ xb,
    int* __restrict__ e0a, int* __restrict__ e1a,
    float* __restrict__ w0a, float* __restrict__ w1a, int* __restrict__ counts)
{
    const int t = blockIdx.x, tid = threadIdx.x;
    float4 xv = ((const float4*)(x + (size_t)t * DM))[tid];
    ((ushort4*)(xb + (size_t)t * DM))[tid] = f4tobf(xv);
    float part[NE];
#pragma unroll
    for (int e = 0; e < NE; ++e) {
        float4 wv = ((const float4*)(rw + (size_t)e * DM))[tid];
        part[e] = xv.x*wv.x + xv.y*wv.y + xv.z*wv.z + xv.w*wv.w;
    }
#pragma unroll
    for (int e = 0; e < NE; ++e) {
        float v = part[e];
#pragma unroll
        for (int off = 32; off > 0; off >>= 1) v += __shfl_down(v, off);
        part[e] = v;
    }
    __shared__ float red[4][NE];
    const int lane = tid & 63, wv_ = tid >> 6;
    if (lane == 0) {
#pragma unroll
        for (int e = 0; e < NE; ++e) red[wv_][e] = part[e];
    }
    __syncthreads();
    if (tid == 0) {
        float lg[NE];
#pragma unroll
        for (int e = 0; e < NE; ++e)
            lg[e] = red[0][e] + red[1][e] + red[2][e] + red[3][e] + rb[e];
        int b0 = 0;
        for (int e = 1; e < NE; ++e) if (lg[e] > lg[b0]) b0 = e;
        int b1 = (b0 == 0) ? 1 : 0;
        for (int e = 0; e < NE; ++e) { if (e == b0) continue; if (lg[e] > lg[b1]) b1 = e; }
        float m  = fmaxf(lg[b0], lg[b1]);
        float x0 = __expf(lg[b0] - m), x1 = __expf(lg[b1] - m);
        float inv = 1.f / (x0 + x1);
        e0a[t] = b0; e1a[t] = b1; w0a[t] = x0 * inv; w1a[t] = x1 * inv;
        atomicAdd(&counts[b0], 1); atomicAdd(&counts[b1], 1);
    }
}

// ---------------- Exclusive scan of 16 counts --------------------------------
__global__ void k_scan(const int* __restrict__ counts, int* __restrict__ offs)
{
    if (threadIdx.x == 0) {
        int s = 0;
        for (int e = 0; e < NE; ++e) { offs[e] = s; s += counts[e]; }
        offs[NE] = s;
    }
}

// ---------------- Scatter token->pair slots ----------------------------------
__global__ __launch_bounds__(256) void k_scatter(
    const int* __restrict__ e0a, const int* __restrict__ e1a,
    const int* __restrict__ offs, int* __restrict__ cursors,
    int* __restrict__ p0a, int* __restrict__ p1a, int* __restrict__ pair_tok)
{
    const int t = blockIdx.x * 256 + threadIdx.x;
    if (t >= T_TOK) return;
    int e0 = e0a[t];
    int p = offs[e0] + atomicAdd(&cursors[e0], 1);
    pair_tok[p] = t; p0a[t] = p;
    int e1 = e1a[t];
    p = offs[e1] + atomicAdd(&cursors[e1], 1);
    pair_tok[p] = t; p1a[t] = p;
}

// ================= bf16-weight GEMM path (global_load_lds, 2-phase) =========
// GEMM1: h = silu(X@W1^T) * (X@W3^T). 128x128 tile, BK=32, 8 waves (2Mx4N).
// LDS linear [128][32] bf16 per tile, double-buffered (48 KB total).
// Staging: 512 threads x 16B = one 8KB tile per gload pass (1 load/thread/tile).
__global__ __launch_bounds__(512) void k_ffn1b(
    const unsigned short* __restrict__ xb, const unsigned short* __restrict__ w1b,
    const unsigned short* __restrict__ w3b, const int* __restrict__ pair_tok,
    const int* __restrict__ offs, const int* __restrict__ counts,
    unsigned short* __restrict__ h)
{
    const int e = blockIdx.z;
    const int cnt = counts[e];
    const int m0 = blockIdx.x * 128;
    if (m0 >= cnt) return;
    const int base = offs[e];
    const int n0 = blockIdx.y * 128;

    __shared__ __attribute__((aligned(16))) unsigned short As[2][128 * 32];
    __shared__ __attribute__((aligned(16))) unsigned short B1s[2][128 * 32];
    __shared__ __attribute__((aligned(16))) unsigned short B3s[2][128 * 32];

    const int tid = threadIdx.x;
    // staging unit: row = tid>>2 (tile row), seg = tid&3 (16B chunk of 64B row)
    const int srow = tid >> 2, sseg = tid & 3;
    const int tok = pair_tok[base + min(m0 + srow, cnt - 1)];
    const unsigned short* gA  = xb  + (size_t)tok * DM + sseg * 8;
    const unsigned short* gB1 = w1b + (size_t)e * FF * DM + (size_t)(n0 + srow) * DM + sseg * 8;
    const unsigned short* gB3 = w3b + (size_t)e * FF * DM + (size_t)(n0 + srow) * DM + sseg * 8;

    const int wave = tid >> 6, lane = tid & 63;
    const int wm = (wave >> 2) * 64, wn = (wave & 3) * 32;
    const int lr = lane & 15, lk = (lane >> 4) * 8;

    f32x4 acc1[4][2], acc3[4][2];
#pragma unroll
    for (int i = 0; i < 4; ++i)
#pragma unroll
        for (int j = 0; j < 2; ++j) {
            acc1[i][j] = f32x4{0.f, 0.f, 0.f, 0.f};
            acc3[i][j] = f32x4{0.f, 0.f, 0.f, 0.f};
        }

    // prologue: stage tile 0
    GLOAD16(gA,  &As [0][tid * 8]);
    GLOAD16(gB1, &B1s[0][tid * 8]);
    GLOAD16(gB3, &B3s[0][tid * 8]);
    __syncthreads();

    int cur = 0;
    for (int k0 = 32; k0 <= DM; k0 += 32) {   // compute tile (k0-32), prefetch k0
        if (k0 < DM) {
            const int nxt = cur ^ 1;
            GLOAD16(gA  + k0, &As [nxt][tid * 8]);
            GLOAD16(gB1 + k0, &B1s[nxt][tid * 8]);
            GLOAD16(gB3 + k0, &B3s[nxt][tid * 8]);
        }
        bf16x8 af[4], b1f[2], b3f[2];
#pragma unroll
        for (int i = 0; i < 4; ++i) af[i] = *(const bf16x8*)&As[cur][(wm + i*16 + lr) * 32 + lk];
#pragma unroll
        for (int j = 0; j < 2; ++j) {
            b1f[j] = *(const bf16x8*)&B1s[cur][(wn + j*16 + lr) * 32 + lk];
            b3f[j] = *(const bf16x8*)&B3s[cur][(wn + j*16 + lr) * 32 + lk];
        }
#pragma unroll
        for (int i = 0; i < 4; ++i)
#pragma unroll
            for (int j = 0; j < 2; ++j) {
                acc1[i][j] = __builtin_amdgcn_mfma_f32_16x16x32_bf16(af[i], b1f[j], acc1[i][j], 0, 0, 0);
                acc3[i][j] = __builtin_amdgcn_mfma_f32_16x16x32_bf16(af[i], b3f[j], acc3[i][j], 0, 0, 0);
            }
        __syncthreads();   // drains prefetch (vmcnt) + guards buffer reuse
        cur ^= 1;
    }

    const int orb = (lane >> 4) * 4, oc = lane & 15;
#pragma unroll
    for (int i = 0; i < 4; ++i) {
#pragma unroll
        for (int r = 0; r < 4; ++r) {
            int m = m0 + wm + i*16 + orb + r;
            if (m < cnt) {
                size_t prow = (size_t)(base + m) * FF + n0 + wn;
#pragma unroll
                for (int j = 0; j < 2; ++j) {
                    float a = acc1[i][j][r], c = acc3[i][j][r];
                    float hv = (a / (1.f + __expf(-a))) * c;   // silu(a)*c
                    h[prow + j*16 + oc] = f2bf(hv);
                }
            }
        }
    }
}

// GEMM2: y = h @ W2^T (fp32 out). Same structure, 2 tiles (32 KB LDS).
__global__ __launch_bounds__(512) void k_ffn2b(
    const unsigned short* __restrict__ h, const unsigned short* __restrict__ w2b,
    const int* __restrict__ offs, const int* __restrict__ counts,
    float* __restrict__ y)
{
    const int e = blockIdx.z;
    const int cnt = counts[e];
    const int m0 = blockIdx.x * 128;
    if (m0 >= cnt) return;
    const int base = offs[e];
    const int n0 = blockIdx.y * 128;

    __shared__ __attribute__((aligned(16))) unsigned short As[2][128 * 32];
    __shared__ __attribute__((aligned(16))) unsigned short Bs[2][128 * 32];

    const int tid = threadIdx.x;
    const int srow = tid >> 2, sseg = tid & 3;
    const unsigned short* gA = h + (size_t)min(base + m0 + srow, NP - 1) * FF + sseg * 8;
    const unsigned short* gB = w2b + (size_t)e * DM * FF + (size_t)(n0 + srow) * FF + sseg * 8;

    const int wave = tid >> 6, lane = tid & 63;
    const int wm = (wave >> 2) * 64, wn = (wave & 3) * 32;
    const int lr = lane & 15, lk = (lane >> 4) * 8;

    f32x4 acc[4][2];
#pragma unroll
    for (int i = 0; i < 4; ++i)
#pragma unroll
        for (int j = 0; j < 2; ++j) acc[i][j] = f32x4{0.f, 0.f, 0.f, 0.f};

    GLOAD16(gA, &As[0][tid * 8]);
    GLOAD16(gB, &Bs[0][tid * 8]);
    __syncthreads();

    int cur = 0;
    for (int k0 = 32; k0 <= FF; k0 += 32) {
        if (k0 < FF) {
            const int nxt = cur ^ 1;
            GLOAD16(gA + k0, &As[nxt][tid * 8]);
            GLOAD16(gB + k0, &Bs[nxt][tid * 8]);
        }
        bf16x8 af[4], bf[2];
#pragma unroll
        for (int i = 0; i < 4; ++i) af[i] = *(const bf16x8*)&As[cur][(wm + i*16 + lr) * 32 + lk];
#pragma unroll
        for (int j = 0; j < 2; ++j) bf[j] = *(const bf16x8*)&Bs[cur][(wn + j*16 + lr) * 32 + lk];
#pragma unroll
        for (int i = 0; i < 4; ++i)
#pragma unroll
            for (int j = 0; j < 2; ++j)
                acc[i][j] = __builtin_amdgcn_mfma_f32_16x16x32_bf16(af[i], bf[j], acc[i][j], 0, 0, 0);
        __syncthreads();
        cur ^= 1;
    }

    const int orb = (lane >> 4) * 4, oc = lane & 15;
#pragma unroll
    for (int i = 0; i < 4; ++i) {
#pragma unroll
        for (int r = 0; r < 4; ++r) {
            int m = m0 + wm + i*16 + orb + r;
            if (m < cnt) {
                size_t yrow = (size_t)(base + m) * DM + n0 + wn;
#pragma unroll
                for (int j = 0; j < 2; ++j) y[yrow + j*16 + oc] = acc[i][j][r];
            }
        }
    }
}

// ================= fp32-weight fallback GEMMs (round-3 versions) ============
__global__ __launch_bounds__(512) void k_ffn1(
    const unsigned short* __restrict__ xb, const float* __restrict__ w1g,
    const float* __restrict__ w3g, const int* __restrict__ pair_tok,
    const int* __restrict__ offs, const int* __restrict__ counts,
    unsigned short* __restrict__ h)
{
    const int e = blockIdx.z;
    const int cnt = counts[e];
    const int m0 = blockIdx.x * 128;
    if (m0 >= cnt) return;
    const int base = offs[e];
    const int n0 = blockIdx.y * 128;
    const float* __restrict__ W1 = w1g + (size_t)e * FF * DM;
    const float* __restrict__ W3 = w3g + (size_t)e * FF * DM;

    __shared__ __attribute__((aligned(16))) unsigned short As[128][LS];
    __shared__ __attribute__((aligned(16))) unsigned short B1s[128][LS];
    __shared__ __attribute__((aligned(16))) unsigned short B3s[128][LS];

    const int tid = threadIdx.x;
    const int ar = tid >> 2, aseg = tid & 3;
    const int tok = pair_tok[base + min(m0 + ar, cnt - 1)];
    const unsigned short* __restrict__ xrow = xb + (size_t)tok * DM + aseg * 8;

    const int br = tid >> 3, bseg = tid & 7;
    const float* __restrict__ W1r0 = W1 + (size_t)(n0 + br) * DM + bseg * 4;
    const float* __restrict__ W1r1 = W1 + (size_t)(n0 + br + 64) * DM + bseg * 4;
    const float* __restrict__ W3r0 = W3 + (size_t)(n0 + br) * DM + bseg * 4;
    const float* __restrict__ W3r1 = W3 + (size_t)(n0 + br + 64) * DM + bseg * 4;

    const int wave = tid >> 6, lane = tid & 63;
    const int wm = (wave >> 2) * 64, wn = (wave & 3) * 32;
    const int lr = lane & 15, lk = (lane >> 4) * 8;

    f32x4 acc1[4][2], acc3[4][2];
#pragma unroll
    for (int i = 0; i < 4; ++i)
#pragma unroll
        for (int j = 0; j < 2; ++j) {
            acc1[i][j] = f32x4{0.f, 0.f, 0.f, 0.f};
            acc3[i][j] = f32x4{0.f, 0.f, 0.f, 0.f};
        }

    for (int k0 = 0; k0 < DM; k0 += 32) {
        *(uint4*)&As[ar][aseg * 8] = *(const uint4*)(xrow + k0);
        float4 a0 = *(const float4*)(W1r0 + k0);
        float4 a1 = *(const float4*)(W1r1 + k0);
        float4 c0 = *(const float4*)(W3r0 + k0);
        float4 c1 = *(const float4*)(W3r1 + k0);
        *(ushort4*)&B1s[br][bseg * 4]      = f4tobf(a0);
        *(ushort4*)&B1s[br + 64][bseg * 4] = f4tobf(a1);
        *(ushort4*)&B3s[br][bseg * 4]      = f4tobf(c0);
        *(ushort4*)&B3s[br + 64][bseg * 4] = f4tobf(c1);
        __syncthreads();
        bf16x8 af[4], b1f[2], b3f[2];
#pragma unroll
        for (int i = 0; i < 4; ++i) af[i] = *(const bf16x8*)&As[wm + i*16 + lr][lk];
#pragma unroll
        for (int j = 0; j < 2; ++j) {
            b1f[j] = *(const bf16x8*)&B1s[wn + j*16 + lr][lk];
            b3f[j] = *(const bf16x8*)&B3s[wn + j*16 + lr][lk];
        }
#pragma unroll
        for (int i = 0; i < 4; ++i)
#pragma unroll
            for (int j = 0; j < 2; ++j) {
                acc1[i][j] = __builtin_amdgcn_mfma_f32_16x16x32_bf16(af[i], b1f[j], acc1[i][j], 0, 0, 0);
                acc3[i][j] = __builtin_amdgcn_mfma_f32_16x16x32_bf16(af[i], b3f[j], acc3[i][j], 0, 0, 0);
            }
        __syncthreads();
    }
    const int orb = (lane >> 4) * 4, oc = lane & 15;
#pragma unroll
    for (int i = 0; i < 4; ++i) {
#pragma unroll
        for (int r = 0; r < 4; ++r) {
            int m = m0 + wm + i*16 + orb + r;
            if (m < cnt) {
                size_t prow = (size_t)(base + m) * FF + n0 + wn;
#pragma unroll
                for (int j = 0; j < 2; ++j) {
                    float a = acc1[i][j][r], c = acc3[i][j][r];
                    float hv = (a / (1.f + __expf(-a))) * c;
                    h[prow + j*16 + oc] = f2bf(hv);
                }
            }
        }
    }
}

__global__ __launch_bounds__(512) void k_ffn2(
    const unsigned short* __restrict__ h, const float* __restrict__ w2g,
    const int* __restrict__ offs, const int* __restrict__ counts,
    float* __restrict__ y)
{
    const int e = blockIdx.z;
    const int cnt = counts[e];
    const int m0 = blockIdx.x * 128;
    if (m0 >= cnt) return;
    const int base = offs[e];
    const int n0 = blockIdx.y * 128;
    const float* __restrict__ W2 = w2g + (size_t)e * DM * FF;

    __shared__ __attribute__((aligned(16))) unsigned short As[128][LS];
    __shared__ __attribute__((aligned(16))) unsigned short Bs[128][LS];

    const int tid = threadIdx.x;
    const int ar = tid >> 2, aseg = tid & 3;
    const size_t arow = (size_t)min(base + m0 + ar, NP - 1) * FF + aseg * 8;

    const int br = tid >> 3, bseg = tid & 7;
    const float* __restrict__ W2r0 = W2 + (size_t)(n0 + br) * FF + bseg * 4;
    const float* __restrict__ W2r1 = W2 + (size_t)(n0 + br + 64) * FF + bseg * 4;

    const int wave = tid >> 6, lane = tid & 63;
    const int wm = (wave >> 2) * 64, wn = (wave & 3) * 32;
    const int lr = lane & 15, lk = (lane >> 4) * 8;

    f32x4 acc[4][2];
#pragma unroll
    for (int i = 0; i < 4; ++i)
#pragma unroll
        for (int j = 0; j < 2; ++j) acc[i][j] = f32x4{0.f, 0.f, 0.f, 0.f};

    for (int k0 = 0; k0 < FF; k0 += 32) {
        *(uint4*)&As[ar][aseg * 8] = *(const uint4*)(h + arow + k0);
        float4 v0 = *(const float4*)(W2r0 + k0);
        float4 v1 = *(const float4*)(W2r1 + k0);
        *(ushort4*)&Bs[br][bseg * 4]      = f4tobf(v0);
        *(ushort4*)&Bs[br + 64][bseg * 4] = f4tobf(v1);
        __syncthreads();
        bf16x8 af[4], bf[2];
#pragma unroll
        for (int i = 0; i < 4; ++i) af[i] = *(const bf16x8*)&As[wm + i*16 + lr][lk];
#pragma unroll
        for (int j = 0; j < 2; ++j) bf[j] = *(const bf16x8*)&Bs[wn + j*16 + lr][lk];
#pragma unroll
        for (int i = 0; i < 4; ++i)
#pragma unroll
            for (int j = 0; j < 2; ++j)
                acc[i][j] = __builtin_amdgcn_mfma_f32_16x16x32_bf16(af[i], bf[j], acc[i][j], 0, 0, 0);
        __syncthreads();
    }
    const int orb = (lane >> 4) * 4, oc = lane & 15;
#pragma unroll
    for (int i = 0; i < 4; ++i) {
#pragma unroll
        for (int r = 0; r < 4; ++r) {
            int m = m0 + wm + i*16 + orb + r;
            if (m < cnt) {
                size_t yrow = (size_t)(base + m) * DM + n0 + wn;
#pragma unroll
                for (int j = 0; j < 2; ++j) y[yrow + j*16 + oc] = acc[i][j][r];
            }
        }
    }
}

// ---------------- LayerNorm both pair rows + weighted combine ---------------
__global__ __launch_bounds__(256) void k_ln(
    const float* __restrict__ y, const int* __restrict__ p0a, const int* __restrict__ p1a,
    const int* __restrict__ e0a, const int* __restrict__ e1a,
    const float* __restrict__ w0a, const float* __restrict__ w1a,
    const float* __restrict__ lng, const float* __restrict__ lnb,
    float* __restrict__ out)
{
    const int t = blockIdx.x, tid = threadIdx.x;
    const int p0 = p0a[t], p1 = p1a[t], e0 = e0a[t], e1 = e1a[t];
    const float cw0 = w0a[t], cw1 = w1a[t];
    float4 y0 = ((const float4*)(y + (size_t)p0 * DM))[tid];
    float4 y1 = ((const float4*)(y + (size_t)p1 * DM))[tid];
    float s0 = y0.x + y0.y + y0.z + y0.w;
    float q0 = y0.x*y0.x + y0.y*y0.y + y0.z*y0.z + y0.w*y0.w;
    float s1 = y1.x + y1.y + y1.z + y1.w;
    float q1 = y1.x*y1.x + y1.y*y1.y + y1.z*y1.z + y1.w*y1.w;
#pragma unroll
    for (int off = 32; off > 0; off >>= 1) {
        s0 += __shfl_down(s0, off); q0 += __shfl_down(q0, off);
        s1 += __shfl_down(s1, off); q1 += __shfl_down(q1, off);
    }
    __shared__ float rbuf[4][4];
    const int lane = tid & 63, wv_ = tid >> 6;
    if (lane == 0) { rbuf[wv_][0] = s0; rbuf[wv_][1] = q0; rbuf[wv_][2] = s1; rbuf[wv_][3] = q1; }
    __syncthreads();
    float S0 = rbuf[0][0] + rbuf[1][0] + rbuf[2][0] + rbuf[3][0];
    float Q0 = rbuf[0][1] + rbuf[1][1] + rbuf[2][1] + rbuf[3][1];
    float S1 = rbuf[0][2] + rbuf[1][2] + rbuf[2][2] + rbuf[3][2];
    float Q1 = rbuf[0][3] + rbuf[1][3] + rbuf[2][3] + rbuf[3][3];
    const float invD = 1.f / (float)DM;
    float mu0 = S0 * invD, mu1 = S1 * invD;
    float rs0 = rsqrtf(fmaxf(Q0 * invD - mu0 * mu0, 0.f) + 1e-5f);
    float rs1 = rsqrtf(fmaxf(Q1 * invD - mu1 * mu1, 0.f) + 1e-5f);
    float4 g0 = ((const float4*)(lng + (size_t)e0 * DM))[tid];
    float4 b0 = ((const float4*)(lnb + (size_t)e0 * DM))[tid];
    float4 g1 = ((const float4*)(lng + (size_t)e1 * DM))[tid];
    float4 b1 = ((const float4*)(lnb + (size_t)e1 * DM))[tid];
    float4 o;
    o.x = cw0 * ((y0.x - mu0) * rs0 * g0.x + b0.x) + cw1 * ((y1.x - mu1) * rs1 * g1.x + b1.x);
    o.y = cw0 * ((y0.y - mu0) * rs0 * g0.y + b0.y) + cw1 * ((y1.y - mu1) * rs1 * g1.y + b1.y);
    o.z = cw0 * ((y0.z - mu0) * rs0 * g0.z + b0.z) + cw1 * ((y1.z - mu1) * rs1 * g1.z + b1.z);
    o.w = cw0 * ((y0.w - mu0) * rs0 * g0.w + b0.w) + cw1 * ((y1.w - mu1) * rs1 * g1.w + b1.w);
    ((float4*)(out + (size_t)t * DM))[tid] = o;
}

// ---------------- launch -----------------------------------------------------
extern "C" void kernel_launch(void* const* d_in, const int* in_sizes, int n_in,
                              void* d_out, int out_size, void* d_ws, size_t ws_size,
                              hipStream_t stream)
{
    const float* x   = (const float*)d_in[0];
    const float* rw  = (const float*)d_in[1];
    const float* rb  = (const float*)d_in[2];
    const float* w1  = (const float*)d_in[3];
    const float* w2  = (const float*)d_in[4];
    const float* w3  = (const float*)d_in[5];
    const float* lng = (const float*)d_in[6];
    const float* lnb = (const float*)d_in[7];
    float* out = (float*)d_out;
    char* ws = (char*)d_ws;

    const size_t OFF_XB   = 0;                                  // 8 MB
    const size_t OFF_H    = OFF_XB + (size_t)T_TOK * DM * 2;    // 32 MB
    const size_t OFF_Y    = OFF_H + (size_t)NP * FF * 2;        // 32 MB
    const size_t OFF_META = OFF_Y + (size_t)NP * DM * 4;
    const size_t OFF_W1B  = OFF_META + (1u << 20);
    const size_t WBYTES   = (size_t)NE * FF * DM * 2;           // 67.1 MB per tensor
    const size_t OFF_W3B  = OFF_W1B + WBYTES;
    const size_t OFF_W2B  = OFF_W3B + WBYTES;
    const size_t NEED     = OFF_W2B + WBYTES;                   // ~265 MB

    unsigned short* xb = (unsigned short*)(ws + OFF_XB);
    unsigned short* h  = (unsigned short*)(ws + OFF_H);
    float* y           = (float*)(ws + OFF_Y);
    int* counts   = (int*)(ws + OFF_META);
    int* cursors  = counts + 16;
    int* offs     = counts + 32;
    int* e0a      = (int*)(ws + OFF_META + 256);
    int* e1a      = e0a + T_TOK;
    float* w0a    = (float*)(e1a + T_TOK);
    float* w1a    = w0a + T_TOK;
    int* p0a      = (int*)(w1a + T_TOK);
    int* p1a      = p0a + T_TOK;
    int* pair_tok = p1a + T_TOK;

    hipMemsetAsync(ws + OFF_META, 0, 128, stream);
    k_router<<<T_TOK, 256, 0, stream>>>(x, rw, rb, xb, e0a, e1a, w0a, w1a, counts);
    k_scan<<<1, 64, 0, stream>>>(counts, offs);
    k_scatter<<<T_TOK / 256, 256, 0, stream>>>(e0a, e1a, offs, cursors, p0a, p1a, pair_tok);

    if (ws_size >= NEED) {
        unsigned short* w1b = (unsigned short*)(ws + OFF_W1B);
        unsigned short* w3b = (unsigned short*)(ws + OFF_W3B);
        unsigned short* w2b = (unsigned short*)(ws + OFF_W2B);
        const int n8 = NE * FF * DM / 8;
        k_convert<<<2048, 256, 0, stream>>>(w1, w1b, n8);
        k_convert<<<2048, 256, 0, stream>>>(w3, w3b, n8);
        k_convert<<<2048, 256, 0, stream>>>(w2, w2b, n8);
        k_ffn1b<<<dim3(32, FF / 128, NE), 512, 0, stream>>>(xb, w1b, w3b, pair_tok, offs, counts, h);
        k_ffn2b<<<dim3(32, DM / 128, NE), 512, 0, stream>>>(h, w2b, offs, counts, y);
    } else {
        k_ffn1<<<dim3(32, FF / 128, NE), 512, 0, stream>>>(xb, w1, w3, pair_tok, offs, counts, h);
        k_ffn2<<<dim3(32, DM / 128, NE), 512, 0, stream>>>(h, w2, offs, counts, y);
    }
    k_ln<<<T_TOK, 256, 0, stream>>>(y, p0a, p1a, e0a, e1a, w0a, w1a, lng, lnb, out);
}